// Round 1
// baseline (418.676 us; speedup 1.0000x reference)
//
#include <hip/hip_runtime.h>
#include <cmath>

namespace {

constexpr int kN = 524288;      // points
constexpr int kL = 16;          // levels
constexpr int kCapLog2 = 19;    // 2^19 table entries per level
constexpr int kCapMask = (1 << kCapLog2) - 1;
constexpr unsigned kHashMult = 2531011u;

struct ScaleArr { float s[kL]; };

__global__ __launch_bounds__(256) void permuto_fwd(
    const float* __restrict__ pos,
    const float* __restrict__ params,
    float* __restrict__ out,
    ScaleArr sc)
{
    const int gid = blockIdx.x * 256 + threadIdx.x;
    const int l = gid & (kL - 1);
    const int n = gid >> 4;

    // Elevation matrix E (D=3 -> D1=4), double-precision constants rounded
    // to f32 exactly like the numpy reference builds it.
    const float E00 = (float)( 0.70710678118654752440);  // 1/sqrt(2)
    const float E01 = (float)( 0.40824829046386301637);  // 1/sqrt(6)
    const float E02 = (float)( 0.28867513459481288225);  // 1/sqrt(12)
    const float E10 = (float)(-0.70710678118654752440);
    const float E21 = (float)(-2.0 * 0.40824829046386301637);
    const float E32 = (float)(-3.0 * 0.28867513459481288225);

    const float s  = sc.s[l];
    const float x0 = pos[3 * n + 0] * s;
    const float x1 = pos[3 * n + 1] * s;
    const float x2 = pos[3 * n + 2] * s;

    float elev[4];
    elev[0] = E00 * x0 + E01 * x1 + E02 * x2;
    elev[1] = E10 * x0 + E01 * x1 + E02 * x2;
    elev[2] =            E21 * x1 + E02 * x2;
    elev[3] =                       E32 * x2;

    float rem0f[4], di[4];
    #pragma unroll
    for (int v = 0; v < 4; ++v) {
        rem0f[v] = rintf(elev[v] * 0.25f) * 4.0f;  // round-half-even, /4 and *4 exact
        di[v]    = elev[v] - rem0f[v];
    }
    const int sums = (int)((((rem0f[0] + rem0f[1]) + rem0f[2]) + rem0f[3]) * 0.25f);

    int rank[4], rem0[4];
    #pragma unroll
    for (int a = 0; a < 4; ++a) {
        int r = 0;
        #pragma unroll
        for (int b = 0; b < 4; ++b) {
            r += (di[b] > di[a]) || (di[b] == di[a] && b < a);
        }
        rank[a] = r + sums;
        rem0[a] = (int)rem0f[a];
    }
    #pragma unroll
    for (int v = 0; v < 4; ++v) {
        if (rank[v] < 0)      { rank[v] += 4; rem0[v] += 4; }
        else if (rank[v] > 3) { rank[v] -= 4; rem0[v] -= 4; }
    }

    // delta sorted by rank: dbr[rank[v]] = delta[v]  (rank is a permutation of 0..3)
    float dbr[4];
    #pragma unroll
    for (int v = 0; v < 4; ++v) {
        dbr[rank[v] & 3] = (elev[v] - (float)rem0[v]) * 0.25f;
    }
    float w[4];
    w[0] = (1.0f + dbr[3]) - dbr[0];
    w[1] = dbr[2] - dbr[3];
    w[2] = dbr[1] - dbr[2];
    w[3] = dbr[0] - dbr[1];

    const float2* __restrict__ tab = (const float2*)params + ((size_t)l << kCapLog2);
    float o0 = 0.0f, o1 = 0.0f;
    #pragma unroll
    for (int k = 0; k < 4; ++k) {
        int h = 0;
        #pragma unroll
        for (int i = 0; i < 3; ++i) {
            const int key = rem0[i] + k - 4 * (rank[i] > 3 - k);
            h = (int)((unsigned)(h + key) * kHashMult);  // int32 wraparound like numpy
        }
        const float2 f = tab[h & kCapMask];
        o0 += w[k] * f.x;
        o1 += w[k] * f.y;
    }

    ((float2*)out)[(n << 4) + l] = make_float2(o0, o1);
}

} // namespace

extern "C" void kernel_launch(void* const* d_in, const int* in_sizes, int n_in,
                              void* d_out, int out_size, void* d_ws, size_t ws_size,
                              hipStream_t stream) {
    const float* pos    = (const float*)d_in[0];
    const float* params = (const float*)d_in[1];
    float* out          = (float*)d_out;

    ScaleArr sc;
    for (int l = 0; l < kL; ++l)
        sc.s[l] = (float)(16.0 * pow(128.0, (double)l / 15.0));  // matches np scales

    const int total = kN * kL;                 // 8,388,608 threads, exact multiple of 256
    permuto_fwd<<<total / 256, 256, 0, stream>>>(pos, params, out, sc);
}

// Round 2
// 197.047 us; speedup vs baseline: 2.1248x; 2.1248x over previous
//
#include <hip/hip_runtime.h>
#include <hip/hip_fp16.h>
#include <cmath>

namespace {

typedef float    vf2 __attribute__((ext_vector_type(2)));
typedef float    vf4 __attribute__((ext_vector_type(4)));
typedef unsigned uv2 __attribute__((ext_vector_type(2)));

constexpr int kN = 524288;      // points
constexpr int kL = 16;          // levels
constexpr int kCapLog2 = 19;
constexpr int kCap = 1 << kCapLog2;
constexpr int kCapMask = kCap - 1;
constexpr unsigned kHashMult = 2531011u;

struct ScaleArr { float s[kL]; };

// ---------------- shared per-thread math (identical numerics to R1) --------
__device__ __forceinline__ void permuto_point(
    float x0, float x1, float x2, int rem0[4], int rank[4], float w[4])
{
    const float E00 = (float)( 0.70710678118654752440);
    const float E01 = (float)( 0.40824829046386301637);
    const float E02 = (float)( 0.28867513459481288225);
    const float E10 = (float)(-0.70710678118654752440);
    const float E21 = (float)(-2.0 * 0.40824829046386301637);
    const float E32 = (float)(-3.0 * 0.28867513459481288225);

    float elev[4];
    elev[0] = E00 * x0 + E01 * x1 + E02 * x2;
    elev[1] = E10 * x0 + E01 * x1 + E02 * x2;
    elev[2] =            E21 * x1 + E02 * x2;
    elev[3] =                       E32 * x2;

    float rem0f[4], di[4];
    #pragma unroll
    for (int v = 0; v < 4; ++v) {
        rem0f[v] = rintf(elev[v] * 0.25f) * 4.0f;
        di[v]    = elev[v] - rem0f[v];
    }
    const int sums = (int)((((rem0f[0] + rem0f[1]) + rem0f[2]) + rem0f[3]) * 0.25f);

    #pragma unroll
    for (int a = 0; a < 4; ++a) {
        int r = 0;
        #pragma unroll
        for (int b = 0; b < 4; ++b)
            r += (di[b] > di[a]) || (di[b] == di[a] && b < a);
        rank[a] = r + sums;
        rem0[a] = (int)rem0f[a];
    }
    #pragma unroll
    for (int v = 0; v < 4; ++v) {
        if (rank[v] < 0)      { rank[v] += 4; rem0[v] += 4; }
        else if (rank[v] > 3) { rank[v] -= 4; rem0[v] -= 4; }
    }

    float dbr[4];
    #pragma unroll
    for (int v = 0; v < 4; ++v)
        dbr[rank[v] & 3] = (elev[v] - (float)rem0[v]) * 0.25f;

    w[0] = (1.0f + dbr[3]) - dbr[0];
    w[1] = dbr[2] - dbr[3];
    w[2] = dbr[1] - dbr[2];
    w[3] = dbr[0] - dbr[1];
}

// ---------------- kernel 1: f32 params -> fp16 table in ws -----------------
__global__ __launch_bounds__(256) void conv_tab(const float* __restrict__ params,
                                                unsigned* __restrict__ tab)
{
    const int i = blockIdx.x * 256 + threadIdx.x;   // one float4 -> one 8B half4
    vf4 v = __builtin_nontemporal_load((const vf4*)params + i);
    __half2 a = __floats2half2_rn(v.x, v.y);
    __half2 b = __floats2half2_rn(v.z, v.w);
    uv2 o;
    o.x = *reinterpret_cast<unsigned*>(&a);
    o.y = *reinterpret_cast<unsigned*>(&b);
    __builtin_nontemporal_store(o, (uv2*)tab + i);
}

// ---------------- kernel 2: level-major main, XCD-affine -------------------
__global__ __launch_bounds__(256) void permuto_main(
    const float* __restrict__ pos,
    const unsigned* __restrict__ tab,   // half2 per table entry
    vf2* __restrict__ out_t,            // [level][point]
    ScaleArr sc)
{
    const int b     = blockIdx.x;
    const int xcd   = b & 7;            // HW round-robins blocks across 8 XCDs
    const int j     = b >> 3;           // 0..4095
    const int level = xcd + ((j >> 11) << 3);   // phase 0: levels 0..7, phase 1: 8..15
    const int n     = ((j & 2047) << 8) + threadIdx.x;

    const float s  = sc.s[level];
    // NT loads: pos is streamed, keep it out of L2 (table owns the L2)
    const float x0 = __builtin_nontemporal_load(pos + 3 * n + 0) * s;
    const float x1 = __builtin_nontemporal_load(pos + 3 * n + 1) * s;
    const float x2 = __builtin_nontemporal_load(pos + 3 * n + 2) * s;

    int rem0[4], rank[4];
    float w[4];
    permuto_point(x0, x1, x2, rem0, rank, w);

    const unsigned* __restrict__ t = tab + ((size_t)level << kCapLog2);
    float o0 = 0.0f, o1 = 0.0f;
    #pragma unroll
    for (int k = 0; k < 4; ++k) {
        int h = 0;
        #pragma unroll
        for (int i = 0; i < 3; ++i) {
            const int key = rem0[i] + k - 4 * (rank[i] > 3 - k);
            h = (int)((unsigned)(h + key) * kHashMult);
        }
        const unsigned e = t[h & kCapMask];          // cacheable: lives in L2
        const __half2 hv = *reinterpret_cast<const __half2*>(&e);
        o0 += w[k] * __low2float(hv);
        o1 += w[k] * __high2float(hv);
    }

    vf2 o; o.x = o0; o.y = o1;
    __builtin_nontemporal_store(o, out_t + (size_t)level * kN + n);
}

// ---------------- kernel 3: [level][point] -> [point][level] transpose -----
__global__ __launch_bounds__(256) void transpose_out(
    const vf2* __restrict__ out_t, vf4* __restrict__ out4)
{
    __shared__ float tile[256][36];     // 36-float row: 16B-aligned float4 reads, ~2-way banks
    const int t  = threadIdx.x;
    const int p0 = blockIdx.x * 256;

    #pragma unroll
    for (int l = 0; l < kL; ++l) {
        vf2 v = __builtin_nontemporal_load(out_t + (size_t)l * kN + p0 + t);
        tile[t][2 * l + 0] = v.x;
        tile[t][2 * l + 1] = v.y;
    }
    __syncthreads();

    const size_t base = (size_t)p0 * 8;           // float4 index of block's output
    #pragma unroll
    for (int i = 0; i < 8; ++i) {
        const int idx = i * 256 + t;              // 0..2047 float4s = 256 pts * 32 floats
        const int p = idx >> 3, q = idx & 7;
        vf4 v = *reinterpret_cast<const vf4*>(&tile[p][4 * q]);
        out4[base + idx] = v;
    }
}

// ---------------- fallback (R1 kernel) if ws is too small ------------------
__global__ __launch_bounds__(256) void permuto_fwd(
    const float* __restrict__ pos,
    const float* __restrict__ params,
    float* __restrict__ out,
    ScaleArr sc)
{
    const int gid = blockIdx.x * 256 + threadIdx.x;
    const int l = gid & (kL - 1);
    const int n = gid >> 4;

    const float s  = sc.s[l];
    const float x0 = pos[3 * n + 0] * s;
    const float x1 = pos[3 * n + 1] * s;
    const float x2 = pos[3 * n + 2] * s;

    int rem0[4], rank[4];
    float w[4];
    permuto_point(x0, x1, x2, rem0, rank, w);

    const float2* __restrict__ tab = (const float2*)params + ((size_t)l << kCapLog2);
    float o0 = 0.0f, o1 = 0.0f;
    #pragma unroll
    for (int k = 0; k < 4; ++k) {
        int h = 0;
        #pragma unroll
        for (int i = 0; i < 3; ++i) {
            const int key = rem0[i] + k - 4 * (rank[i] > 3 - k);
            h = (int)((unsigned)(h + key) * kHashMult);
        }
        const float2 f = tab[h & kCapMask];
        o0 += w[k] * f.x;
        o1 += w[k] * f.y;
    }
    ((float2*)out)[(n << 4) + l] = make_float2(o0, o1);
}

} // namespace

extern "C" void kernel_launch(void* const* d_in, const int* in_sizes, int n_in,
                              void* d_out, int out_size, void* d_ws, size_t ws_size,
                              hipStream_t stream) {
    const float* pos    = (const float*)d_in[0];
    const float* params = (const float*)d_in[1];
    float* out          = (float*)d_out;

    ScaleArr sc;
    for (int l = 0; l < kL; ++l)
        sc.s[l] = (float)(16.0 * pow(128.0, (double)l / 15.0));

    const size_t tab_bytes  = (size_t)kL * kCap * 4;   // fp16 table: 32 MiB
    const size_t outt_bytes = (size_t)kL * kN * 8;     // level-major out: 64 MiB

    if (ws_size >= tab_bytes + outt_bytes) {
        unsigned* tab = (unsigned*)d_ws;
        vf2* out_t    = (vf2*)((char*)d_ws + tab_bytes);

        // 16.7M floats / 4 per thread / 256 per block
        conv_tab<<<(kL * kCap * 2 / 4) / 256, 256, 0, stream>>>(params, tab);
        // 16 levels * 2048 point-chunks
        permuto_main<<<kL * (kN / 256), 256, 0, stream>>>(pos, tab, out_t, sc);
        // 2048 blocks of 256 points
        transpose_out<<<kN / 256, 256, 0, stream>>>(out_t, (vf4*)out);
    } else {
        permuto_fwd<<<(kN * kL) / 256, 256, 0, stream>>>(pos, params, out, sc);
    }
}